// Round 10
// baseline (336.424 us; speedup 1.0000x reference)
//
#include <hip/hip_runtime.h>
#include <hip/hip_bf16.h>

// CrossAttention: out = softmax((X Wq)(KV Wk)^T / 8) (KV Wv) Wc
// B=2 S=T=2048 H=1024 nh=16 hd=64
// R10: gemm_qkv -> 128x64 tiles, 1536 blocks = 6 blocks/CU (was 768 = 3,
//      grid-limited; 90% of iter cycles were uncovered barrier/latency
//      stalls). LDS 24KB, launch_bounds(256,6). All else frozen from R9.

typedef unsigned short u16;
typedef __attribute__((ext_vector_type(4))) float float4v;
typedef __attribute__((ext_vector_type(4))) unsigned short u16x4;
typedef __attribute__((ext_vector_type(8))) short short8;
typedef __attribute__((ext_vector_type(4))) float floatx4;

__device__ __forceinline__ u16 f2bf(float f) {
  unsigned u = __float_as_uint(f);
  u += 0x7fffu + ((u >> 16) & 1u);   // RNE
  return (u16)(u >> 16);
}

__device__ __forceinline__ float fast_exp2(float x) {
#if __has_builtin(__builtin_amdgcn_exp2f)
  return __builtin_amdgcn_exp2f(x);
#else
  return exp2f(x);
#endif
}

__device__ __forceinline__ unsigned pack_bf2(float a, float b) {
#if __has_builtin(__builtin_amdgcn_cvt_pk_bf16_f32)
  auto r = __builtin_amdgcn_cvt_pk_bf16_f32(a, b);
  unsigned u;
  __builtin_memcpy(&u, &r, 4);
  return u;
#else
  unsigned ua = __float_as_uint(a) + 0x7fffu + ((__float_as_uint(a) >> 16) & 1u);
  unsigned ub = __float_as_uint(b) + 0x7fffu + ((__float_as_uint(b) >> 16) & 1u);
  return __builtin_amdgcn_perm(ub, ua, 0x07060302u);
#endif
}

__device__ __forceinline__ void gld16(const void* g, void* l) {
  __builtin_amdgcn_global_load_lds(
      (const __attribute__((address_space(1))) void*)g,
      (__attribute__((address_space(3))) void*)l, 16, 0, 0);
}

// row swizzle for 32-elem (4-chunk) LDS rows
__device__ __forceinline__ int swz4(int r) { return (r & 3) ^ ((r >> 2) & 3); }

// ---------------- prep: activation cvt + weight transposes, one launch ------
__global__ void prep(const float* __restrict__ X, const float* __restrict__ KV,
                     const float* __restrict__ Wq, const float* __restrict__ Wkv,
                     const float* __restrict__ Wc,
                     u16* __restrict__ qin, u16* __restrict__ kvin,
                     u16* __restrict__ Wqt, u16* __restrict__ Wkvt,
                     u16* __restrict__ Wct) {
  __shared__ float tile[32][33];
  const int bid = blockIdx.x, t = threadIdx.x;
  if (bid < 8192) {
    const float* src = bid < 4096 ? X : KV;
    u16* dst = bid < 4096 ? qin : kvin;
    int i = (bid & 4095) * 256 + t;
    float4v v = ((const float4v*)src)[i];
    u16x4 o;
    o.x = f2bf(v.x); o.y = f2bf(v.y); o.z = f2bf(v.z); o.w = f2bf(v.w);
    ((u16x4*)dst)[i] = o;
  } else {
    int r = bid - 8192;
    const float* in;
    u16* out;
    int C, bx, by;
    if (r < 1024)      { in = Wq;  out = Wqt;  C = 1024; bx = r & 31; by = r >> 5; }
    else if (r < 3072) { r -= 1024; in = Wkv; out = Wkvt; C = 2048; bx = r & 63; by = r >> 6; }
    else               { r -= 3072; in = Wc;  out = Wct;  C = 1024; bx = r & 31; by = r >> 5; }
    const int tx = t & 31, ty = t >> 5;   // 32 x 8
#pragma unroll
    for (int i = 0; i < 32; i += 8)
      tile[ty + i][tx] = in[(size_t)(by * 32 + ty + i) * C + bx * 32 + tx];
    __syncthreads();
#pragma unroll
    for (int i = 0; i < 32; i += 8)
      out[(size_t)(bx * 32 + ty + i) * 1024 + by * 32 + tx] = f2bf(tile[tx][ty + i]);
  }
}

// ======= fused q/k/v projection (bf16), 128x64 tile, BK=32, dbuf ============
// 1536 blocks = 6/CU. bx 0..15: q; 16..31: k; 32..47: v (swapped MFMA ->
// vt direct transpose). LDS-repacked full-line epilogues. XCD patch swizzle.
__global__ __launch_bounds__(256, 6) void gemm_qkv(const u16* __restrict__ qin,
                                                   const u16* __restrict__ kvin,
                                                   const u16* __restrict__ Wqt,
                                                   const u16* __restrict__ Wkvt,
                                                   u16* __restrict__ qp,
                                                   u16* __restrict__ kp,
                                                   u16* __restrict__ vt,
                                                   float qscale) {
  __shared__ __align__(16) u16 Shm[12288];   // 24 KB: As 2*4096 | Bs 2*2048
  u16* As = Shm;
  u16* Bs = Shm + 8192;
  const int t = threadIdx.x;
  const int w = t >> 6, l = t & 63;
  const int lane15 = l & 15, quad = l >> 4;
  const int wm = w >> 1, wn = w & 1;

  // XCD patch swizzle: 192 blocks/XCD as 24(bx) x 8(by)
  const int bid = blockIdx.x;
  const int xr = bid & 7, g = bid >> 3;          // g in [0,192)
  const int bx = 24 * (xr & 1) + g % 24;         // [0,48)
  const int by = 8 * (xr >> 1) + g / 24;         // [0,32)
  const int bm = by * 128;

  const int mode = bx >> 4;                 // 0=q 1=k 2=v
  const int local = bx & 15;
  const u16* A = (mode == 0) ? qin : kvin;
  const u16* Bt = (mode == 0) ? Wqt : Wkvt;
  const int bn = (mode == 2) ? 1024 + local * 64 : local * 64;

  const int srow = t >> 2;                            // 0..63
  const int scol = (((t & 3) ^ swz4(srow)) << 3);
  const u16* ag0 = A + (size_t)(bm + srow) * 1024 + scol;
  const u16* ag1 = ag0 + (size_t)64 * 1024;
  const u16* bg0 = Bt + (size_t)(bn + srow) * 1024 + scol;   // rows 0..63

  int afo[4], bfo[2];
#pragma unroll
  for (int mi = 0; mi < 4; ++mi) {
    int row = wm * 64 + mi * 16 + lane15;
    afo[mi] = row * 32 + ((quad ^ swz4(row)) << 3);
  }
#pragma unroll
  for (int ni = 0; ni < 2; ++ni) {
    int row = wn * 32 + ni * 16 + lane15;
    bfo[ni] = row * 32 + ((quad ^ swz4(row)) << 3);
  }

  floatx4 acc[4][2] = {};
  const bool vswap = (mode == 2);

  auto stage = [&](int kt, int buf) {
    gld16(ag0 + kt, &As[buf * 4096 + t * 8]);
    gld16(ag1 + kt, &As[buf * 4096 + 2048 + t * 8]);
    gld16(bg0 + kt, &Bs[buf * 2048 + t * 8]);
  };
  auto compute = [&](int buf) {
    short8 af[4], bf[2];
#pragma unroll
    for (int mi = 0; mi < 4; ++mi) af[mi] = *(const short8*)&As[buf * 4096 + afo[mi]];
#pragma unroll
    for (int ni = 0; ni < 2; ++ni) bf[ni] = *(const short8*)&Bs[buf * 2048 + bfo[ni]];
    if (!vswap) {
#pragma unroll
      for (int mi = 0; mi < 4; ++mi)
#pragma unroll
        for (int ni = 0; ni < 2; ++ni)
          acc[mi][ni] = __builtin_amdgcn_mfma_f32_16x16x32_bf16(af[mi], bf[ni],
                                                                acc[mi][ni], 0, 0, 0);
    } else {
#pragma unroll
      for (int mi = 0; mi < 4; ++mi)
#pragma unroll
        for (int ni = 0; ni < 2; ++ni)
          acc[mi][ni] = __builtin_amdgcn_mfma_f32_16x16x32_bf16(bf[ni], af[mi],
                                                                acc[mi][ni], 0, 0, 0);
    }
  };

  stage(0, 0);
  __syncthreads();
  for (int kt = 0; kt < 1024; kt += 64) {
    if (kt + 32 < 1024) stage(kt + 32, 1);
    compute(0);
    __syncthreads();
    if (kt + 64 < 1024) stage(kt + 64, 0);
    compute(1);
    __syncthreads();
  }

  // ---- LDS-repacked epilogue: scatter C-layout -> Shm, full-line stores ----
  const float scale = (mode == 0) ? qscale : 1.0f;
  __syncthreads();
  if (!vswap) {
    // tile [128 m][64 n]
#pragma unroll
    for (int mi = 0; mi < 4; ++mi)
#pragma unroll
      for (int ni = 0; ni < 2; ++ni)
#pragma unroll
        for (int r = 0; r < 4; ++r) {
          int rl = wm * 64 + mi * 16 + quad * 4 + r;
          int cl = wn * 32 + ni * 16 + lane15;
          Shm[rl * 64 + (cl ^ ((rl & 3) << 4))] = f2bf(acc[mi][ni][r] * scale);
        }
    __syncthreads();
    u16* dst = (mode == 0) ? qp : kp;
#pragma unroll
    for (int j = 0; j < 4; ++j) {
      int c = t + j * 256;           // 1024 chunks of 8 u16
      int row = c >> 3, ch = c & 7;
      short8 v = *(const short8*)&Shm[row * 64 + ((ch ^ ((row & 3) << 1)) << 3)];
      *(short8*)&dst[(size_t)(bm + row) * 1024 + bn + ch * 8] = v;
    }
  } else {
    // tile [64 wc][128 t]
#pragma unroll
    for (int mi = 0; mi < 4; ++mi)
#pragma unroll
      for (int ni = 0; ni < 2; ++ni)
#pragma unroll
        for (int r = 0; r < 4; ++r) {
          int rl = wn * 32 + ni * 16 + quad * 4 + r;
          int cl = wm * 64 + mi * 16 + lane15;
          Shm[rl * 128 + (cl ^ ((rl & 3) << 4))] = f2bf(acc[mi][ni][r]);
        }
    __syncthreads();
    const int b = bm >> 11, tcol = bm & 2047;
#pragma unroll
    for (int j = 0; j < 4; ++j) {
      int c = t + j * 256;           // 1024 chunks of 8 u16
      int row = c >> 4, ch = c & 15;
      short8 v = *(const short8*)&Shm[row * 128 + ((ch ^ ((row & 3) << 1)) << 3)];
      *(short8*)&vt[(size_t)(b * 1024 + (bn - 1024) + row) * 2048 + tcol + ch * 8] = v;
    }
  }
}

// ============== output projection: 128x64, BK=32, dbuf, repacked fp32 =======
__global__ __launch_bounds__(256, 4) void gemm_out(const u16* __restrict__ A,
                                                   const u16* __restrict__ Bt,
                                                   float* __restrict__ C) {
  __shared__ __align__(16) u16 Shm[16384];   // 32 KB; loop uses 24, epi 32
  u16* As = Shm;                             // 2*4096
  u16* Bs = Shm + 8192;                      // 2*2048
  float* Shf = (float*)Shm;                  // epilogue: [128][64] fp32
  const int t = threadIdx.x;
  const int w = t >> 6, l = t & 63;
  const int lane15 = l & 15, quad = l >> 4;
  const int wm = w >> 1, wn = w & 1;

  const int bid = blockIdx.x;                // 512 blocks
  const int xr = bid & 7, g = bid >> 3;      // g in [0,64)
  const int bx = 8 * (xr & 1) + g % 8;       // [0,16)
  const int by = 8 * (xr >> 1) + g / 8;      // [0,32)
  const int bm = by * 128, bn = bx * 64;

  const int srow = t >> 2;
  const int scol = (((t & 3) ^ swz4(srow)) << 3);
  const u16* ag0 = A + (size_t)(bm + srow) * 1024 + scol;
  const u16* ag1 = ag0 + (size_t)64 * 1024;
  const u16* bg0 = Bt + (size_t)(bn + srow) * 1024 + scol;

  int afo[4], bfo[2];
#pragma unroll
  for (int mi = 0; mi < 4; ++mi) {
    int row = wm * 64 + mi * 16 + lane15;
    afo[mi] = row * 32 + ((quad ^ swz4(row)) << 3);
  }
#pragma unroll
  for (int ni = 0; ni < 2; ++ni) {
    int row = wn * 32 + ni * 16 + lane15;
    bfo[ni] = row * 32 + ((quad ^ swz4(row)) << 3);
  }

  floatx4 acc[4][2] = {};

  auto stage = [&](int kt, int buf) {
    gld16(ag0 + kt, &As[buf * 4096 + t * 8]);
    gld16(ag1 + kt, &As[buf * 4096 + 2048 + t * 8]);
    gld16(bg0 + kt, &Bs[buf * 2048 + t * 8]);
  };
  auto compute = [&](int buf) {
    short8 af[4], bf[2];
#pragma unroll
    for (int mi = 0; mi < 4; ++mi) af[mi] = *(const short8*)&As[buf * 4096 + afo[mi]];
#pragma unroll
    for (int ni = 0; ni < 2; ++ni) bf[ni] = *(const short8*)&Bs[buf * 2048 + bfo[ni]];
#pragma unroll
    for (int mi = 0; mi < 4; ++mi)
#pragma unroll
      for (int ni = 0; ni < 2; ++ni)
        acc[mi][ni] = __builtin_amdgcn_mfma_f32_16x16x32_bf16(af[mi], bf[ni],
                                                              acc[mi][ni], 0, 0, 0);
  };

  stage(0, 0);
  __syncthreads();
  for (int kt = 0; kt < 1024; kt += 64) {
    if (kt + 32 < 1024) stage(kt + 32, 1);
    compute(0);
    __syncthreads();
    if (kt + 64 < 1024) stage(kt + 64, 0);
    compute(1);
    __syncthreads();
  }

  __syncthreads();
#pragma unroll
  for (int mi = 0; mi < 4; ++mi)
#pragma unroll
    for (int ni = 0; ni < 2; ++ni)
#pragma unroll
      for (int r = 0; r < 4; ++r) {
        int rl = wm * 64 + mi * 16 + quad * 4 + r;
        int cl = wn * 32 + ni * 16 + lane15;
        Shf[rl * 64 + (cl ^ ((rl & 3) << 4))] = acc[mi][ni][r];
      }
  __syncthreads();
#pragma unroll
  for (int j = 0; j < 8; ++j) {
    int c = t + j * 256;             // 2048 chunks of float4
    int row = c >> 4, ch = c & 15;
    float4v v = *(const float4v*)&Shf[row * 64 + ((ch ^ ((row & 3) << 2)) << 2)];
    *(float4v*)&C[(size_t)(bm + row) * 1024 + bn + ch * 4] = v;
  }
}

// ---------------- flash attention (S^T layout, BM=128, 8 waves, dbuf x2) ----
__global__ __launch_bounds__(512) void attn_kern(const u16* __restrict__ Q,
                                                 const u16* __restrict__ KP,
                                                 const u16* __restrict__ VT,
                                                 u16* __restrict__ Y) {
  __shared__ __align__(16) u16 Ks[2 * 4096];
  __shared__ __align__(16) u16 VTs[2 * 4096];
  __shared__ __align__(16) u16 Ps[8192];
  const int t = threadIdx.x, w = t >> 6, l = t & 63;
  const int lane15 = l & 15, quad = l >> 4;

  const int bid = blockIdx.x;
  const int xr = bid & 7, g = bid >> 3;     // g in [0,64)
  const int bxt = 8 * (xr & 1) + g % 8;     // [0,16)
  const int bh = 8 * (xr >> 1) + g / 8;     // [0,32)
  const int b = bh >> 4, h = bh & 15;
  const int qrow0 = b * 2048 + bxt * 128;
  const int xm = lane15 & 7;

  short8 qf[2];
#pragma unroll
  for (int ks = 0; ks < 2; ++ks)
    qf[ks] = *(const short8*)&Q[(size_t)(qrow0 + w * 16 + lane15) * 1024 +
                                h * 64 + ks * 32 + quad * 8];

  const short8 vones = {0x3F80, 0x3F80, 0x3F80, 0x3F80,
                        0x3F80, 0x3F80, 0x3F80, 0x3F80};

  floatx4 yacc[4] = {};
  floatx4 lacc = {};

  const int srow = t >> 3;                          // 0..63
  const int scol = (((t & 7) ^ (srow & 7)) << 3);
  const u16* kg = KP + (size_t)(b * 2048 + srow) * 1024 + h * 64 + scol;
  const u16* vg = VT + (size_t)(bh * 64 + srow) * 2048 + scol;

  const int prow = (w * 16 + lane15) * 64;
  int kfo[2][4], vfo[2][4], pwo[4], pro[2];
#pragma unroll
  for (int ks = 0; ks < 2; ++ks)
#pragma unroll
    for (int ti = 0; ti < 4; ++ti)
      kfo[ks][ti] = (ti * 16 + lane15) * 64 + (((ks * 4 + quad) ^ xm) << 3);
#pragma unroll
  for (int ts = 0; ts < 2; ++ts) {
#pragma unroll
    for (int ni = 0; ni < 4; ++ni)
      vfo[ts][ni] = (ni * 16 + lane15) * 64 + (((ts * 4 + quad) ^ xm) << 3);
    pro[ts] = prow + (((ts * 4 + quad) ^ xm) << 3);
  }
#pragma unroll
  for (int ti = 0; ti < 4; ++ti)
    pwo[ti] = prow + (((ti * 2 + (quad >> 1)) ^ xm) << 3) + ((quad & 1) << 2);

  auto stage = [&](int t0n, int buf) {
    gld16(kg + (size_t)t0n * 1024, &Ks[buf + t * 8]);
    gld16(vg + t0n, &VTs[buf + t * 8]);
  };
  auto compute = [&](int buf) {
    floatx4 sacc[4] = {};
#pragma unroll
    for (int ks = 0; ks < 2; ++ks)
#pragma unroll
      for (int ti = 0; ti < 4; ++ti) {
        short8 kf = *(const short8*)&Ks[buf + kfo[ks][ti]];
        sacc[ti] = __builtin_amdgcn_mfma_f32_16x16x32_bf16(kf, qf[ks], sacc[ti], 0, 0, 0);
      }
#pragma unroll
    for (int ti = 0; ti < 4; ++ti) {
      float p0 = fast_exp2(sacc[ti][0]);
      float p1 = fast_exp2(sacc[ti][1]);
      float p2 = fast_exp2(sacc[ti][2]);
      float p3 = fast_exp2(sacc[ti][3]);
      uint2 pk;
      pk.x = pack_bf2(p0, p1);
      pk.y = pack_bf2(p2, p3);
      *(uint2*)&Ps[pwo[ti]] = pk;
    }
#pragma unroll
    for (int ts = 0; ts < 2; ++ts) {
      short8 pf = *(const short8*)&Ps[pro[ts]];
      lacc = __builtin_amdgcn_mfma_f32_16x16x32_bf16(pf, vones, lacc, 0, 0, 0);
#pragma unroll
      for (int ni = 0; ni < 4; ++ni) {
        short8 vf = *(const short8*)&VTs[buf + vfo[ts][ni]];
        yacc[ni] = __builtin_amdgcn_mfma_f32_16x16x32_bf16(pf, vf, yacc[ni], 0, 0, 0);
      }
    }
  };

  stage(0, 0);
  __syncthreads();
  for (int t0 = 0; t0 < 2048; t0 += 128) {
    if (t0 + 64 < 2048) stage(t0 + 64, 4096);
    compute(0);
    __syncthreads();
    if (t0 + 128 < 2048) stage(t0 + 128, 0);
    compute(4096);
    __syncthreads();
  }

#pragma unroll
  for (int r = 0; r < 4; ++r) {
    float linv = 1.0f / lacc[r];
    int row = qrow0 + w * 16 + quad * 4 + r;
#pragma unroll
    for (int ni = 0; ni < 4; ++ni)
      Y[(size_t)row * 1024 + h * 64 + ni * 16 + lane15] = f2bf(yacc[ni][r] * linv);
  }
}

// ---------------- launch ----------------
extern "C" void kernel_launch(void* const* d_in, const int* in_sizes, int n_in,
                              void* d_out, int out_size, void* d_ws, size_t ws_size,
                              hipStream_t stream) {
  const float* query = (const float*)d_in[0];
  const float* key_value = (const float*)d_in[1];
  const float* Wq = (const float*)d_in[2];
  const float* Wkv = (const float*)d_in[3];
  const float* Wc = (const float*)d_in[4];
  float* out = (float*)d_out;

  const size_t MB = 1024 * 1024;
  char* ws = (char*)d_ws;
  u16* qin  = (u16*)(ws + 0 * MB);
  u16* kvin = (u16*)(ws + 8 * MB);
  u16* Wqt  = (u16*)(ws + 16 * MB);
  u16* Wkvt = (u16*)(ws + 18 * MB);
  u16* Wct  = (u16*)(ws + 22 * MB);
  u16* qp   = (u16*)(ws + 24 * MB);
  u16* kp   = (u16*)(ws + 32 * MB);
  u16* vt   = (u16*)(ws + 40 * MB);
  u16* y    = (u16*)(ws + 48 * MB);

  prep<<<dim3(12288), dim3(256), 0, stream>>>(query, key_value, Wq, Wkv, Wc,
                                              qin, kvin, Wqt, Wkvt, Wct);
  const float qscale = 0.125f * 1.4426950408889634f;
  gemm_qkv<<<dim3(1536), dim3(256), 0, stream>>>(qin, kvin, Wqt, Wkvt,
                                                 qp, kp, vt, qscale);
  attn_kern<<<dim3(512), dim3(512), 0, stream>>>(qp, kp, vt, y);
  gemm_out<<<dim3(512), dim3(256), 0, stream>>>(y, Wct, out);
}

// Round 11
// 189.600 us; speedup vs baseline: 1.7744x; 1.7744x over previous
//
#include <hip/hip_runtime.h>
#include <hip/hip_bf16.h>

// CrossAttention: out = softmax((X Wq)(KV Wk)^T / 8) (KV Wv) Wc
// B=2 S=T=2048 H=1024 nh=16 hd=64
// R11: revert to R9 (R10 traffic explosion: half-line epilogue stores +
//      oversized per-XCD patches). New: AITER-style K-loop on gemm_qkv and
//      gemm_out — triple-buffered LDS, prefetch distance 2, raw
//      `s_waitcnt vmcnt(N) ; s_barrier` (never vmcnt(0) in steady state).

typedef unsigned short u16;
typedef __attribute__((ext_vector_type(4))) float float4v;
typedef __attribute__((ext_vector_type(4))) unsigned short u16x4;
typedef __attribute__((ext_vector_type(8))) short short8;
typedef __attribute__((ext_vector_type(4))) float floatx4;

__device__ __forceinline__ u16 f2bf(float f) {
  unsigned u = __float_as_uint(f);
  u += 0x7fffu + ((u >> 16) & 1u);   // RNE
  return (u16)(u >> 16);
}

__device__ __forceinline__ float fast_exp2(float x) {
#if __has_builtin(__builtin_amdgcn_exp2f)
  return __builtin_amdgcn_exp2f(x);
#else
  return exp2f(x);
#endif
}

__device__ __forceinline__ unsigned pack_bf2(float a, float b) {
#if __has_builtin(__builtin_amdgcn_cvt_pk_bf16_f32)
  auto r = __builtin_amdgcn_cvt_pk_bf16_f32(a, b);
  unsigned u;
  __builtin_memcpy(&u, &r, 4);
  return u;
#else
  unsigned ua = __float_as_uint(a) + 0x7fffu + ((__float_as_uint(a) >> 16) & 1u);
  unsigned ub = __float_as_uint(b) + 0x7fffu + ((__float_as_uint(b) >> 16) & 1u);
  return __builtin_amdgcn_perm(ub, ua, 0x07060302u);
#endif
}

__device__ __forceinline__ void gld16(const void* g, void* l) {
  __builtin_amdgcn_global_load_lds(
      (const __attribute__((address_space(1))) void*)g,
      (__attribute__((address_space(3))) void*)l, 16, 0, 0);
}

// barrier that leaves the newest N vector-loads in flight
#define WBAR(N) asm volatile("s_waitcnt vmcnt(" #N ") lgkmcnt(0)\n\ts_barrier" ::: "memory")

// row swizzle for 32-elem (4-chunk) LDS rows
__device__ __forceinline__ int swz4(int r) { return (r & 3) ^ ((r >> 2) & 3); }

// ---------------- prep: activation cvt + weight transposes, one launch ------
__global__ void prep(const float* __restrict__ X, const float* __restrict__ KV,
                     const float* __restrict__ Wq, const float* __restrict__ Wkv,
                     const float* __restrict__ Wc,
                     u16* __restrict__ qin, u16* __restrict__ kvin,
                     u16* __restrict__ Wqt, u16* __restrict__ Wkvt,
                     u16* __restrict__ Wct) {
  __shared__ float tile[32][33];
  const int bid = blockIdx.x, t = threadIdx.x;
  if (bid < 8192) {
    const float* src = bid < 4096 ? X : KV;
    u16* dst = bid < 4096 ? qin : kvin;
    int i = (bid & 4095) * 256 + t;
    float4v v = ((const float4v*)src)[i];
    u16x4 o;
    o.x = f2bf(v.x); o.y = f2bf(v.y); o.z = f2bf(v.z); o.w = f2bf(v.w);
    ((u16x4*)dst)[i] = o;
  } else {
    int r = bid - 8192;
    const float* in;
    u16* out;
    int C, bx, by;
    if (r < 1024)      { in = Wq;  out = Wqt;  C = 1024; bx = r & 31; by = r >> 5; }
    else if (r < 3072) { r -= 1024; in = Wkv; out = Wkvt; C = 2048; bx = r & 63; by = r >> 6; }
    else               { r -= 3072; in = Wc;  out = Wct;  C = 1024; bx = r & 31; by = r >> 5; }
    const int tx = t & 31, ty = t >> 5;   // 32 x 8
#pragma unroll
    for (int i = 0; i < 32; i += 8)
      tile[ty + i][tx] = in[(size_t)(by * 32 + ty + i) * C + bx * 32 + tx];
    __syncthreads();
#pragma unroll
    for (int i = 0; i < 32; i += 8)
      out[(size_t)(bx * 32 + ty + i) * 1024 + by * 32 + tx] = f2bf(tile[tx][ty + i]);
  }
}

// ======= fused q/k/v projection (bf16), 128x128, BK=32, 3-buf pipeline ======
// 768 blocks (3/CU). bx 0..7: q; 8..15: k; 16..23: v (swapped MFMA -> vt
// direct transpose). LDS 48KB. Prefetch distance 2, vmcnt(4) barriers.
__global__ __launch_bounds__(256, 3) void gemm_qkv(const u16* __restrict__ qin,
                                                   const u16* __restrict__ kvin,
                                                   const u16* __restrict__ Wqt,
                                                   const u16* __restrict__ Wkvt,
                                                   u16* __restrict__ qp,
                                                   u16* __restrict__ kp,
                                                   u16* __restrict__ vt,
                                                   float qscale) {
  __shared__ __align__(16) u16 Shm[24576];   // 48 KB: As 3*4096 | Bs 3*4096
  u16* As = Shm;
  u16* Bs = Shm + 12288;
  const int t = threadIdx.x;
  const int w = t >> 6, l = t & 63;
  const int lane15 = l & 15, quad = l >> 4;
  const int wm = w >> 1, wn = w & 1;

  // XCD patch swizzle: XCD r gets bx in [12*(r&1),+12), by in [8*(r>>1),+8)
  const int bid = blockIdx.x;
  const int xr = bid & 7, g = bid >> 3;          // g in [0,96)
  const int bx = 12 * (xr & 1) + g % 12;
  const int by = 8 * (xr >> 1) + g / 12;
  const int bm = by * 128;

  const int mode = bx >> 3;                 // 0=q 1=k 2=v
  const u16* A = (mode == 0) ? qin : kvin;
  const u16* Bt = (mode == 0) ? Wqt : Wkvt;
  const int bn = (mode == 2) ? 1024 + (bx - 16) * 128 : (bx & 7) * 128;

  const int srow = t >> 2;                            // 0..63
  const int scol = (((t & 3) ^ swz4(srow)) << 3);
  const u16* ag0 = A + (size_t)(bm + srow) * 1024 + scol;
  const u16* ag1 = ag0 + (size_t)64 * 1024;
  const u16* bg0 = Bt + (size_t)(bn + srow) * 1024 + scol;
  const u16* bg1 = bg0 + (size_t)64 * 1024;

  int afo[4], bfo[4];
#pragma unroll
  for (int mi = 0; mi < 4; ++mi) {
    int row = wm * 64 + mi * 16 + lane15;
    afo[mi] = row * 32 + ((quad ^ swz4(row)) << 3);
  }
#pragma unroll
  for (int ni = 0; ni < 4; ++ni) {
    int row = wn * 64 + ni * 16 + lane15;
    bfo[ni] = row * 32 + ((quad ^ swz4(row)) << 3);
  }

  floatx4 acc[4][4] = {};
  const bool vswap = (mode == 2);

  auto stage = [&](int kt, int buf) {
    gld16(ag0 + kt, &As[buf * 4096 + t * 8]);
    gld16(ag1 + kt, &As[buf * 4096 + 2048 + t * 8]);
    gld16(bg0 + kt, &Bs[buf * 4096 + t * 8]);
    gld16(bg1 + kt, &Bs[buf * 4096 + 2048 + t * 8]);
  };
  auto compute = [&](int buf) {
    short8 af[4], bf[4];
#pragma unroll
    for (int mi = 0; mi < 4; ++mi) af[mi] = *(const short8*)&As[buf * 4096 + afo[mi]];
#pragma unroll
    for (int ni = 0; ni < 4; ++ni) bf[ni] = *(const short8*)&Bs[buf * 4096 + bfo[ni]];
    if (!vswap) {
#pragma unroll
      for (int mi = 0; mi < 4; ++mi)
#pragma unroll
        for (int ni = 0; ni < 4; ++ni)
          acc[mi][ni] = __builtin_amdgcn_mfma_f32_16x16x32_bf16(af[mi], bf[ni],
                                                                acc[mi][ni], 0, 0, 0);
    } else {
#pragma unroll
      for (int mi = 0; mi < 4; ++mi)
#pragma unroll
        for (int ni = 0; ni < 4; ++ni)
          acc[mi][ni] = __builtin_amdgcn_mfma_f32_16x16x32_bf16(bf[ni], af[mi],
                                                                acc[mi][ni], 0, 0, 0);
    }
  };

  // 3-buf pipeline over 32 K-steps: stage(i) lands in buf i%3, consumed 2
  // iters later. Barrier leaves newest 4 loads (next buf) in flight.
  stage(0, 0);
  stage(32, 1);
#pragma unroll
  for (int it = 0; it < 30; ++it) {
    WBAR(4);
    compute(it % 3);
    stage((it + 2) * 32, (it + 2) % 3);
  }
  WBAR(4);
  compute(0);          // it=30
  WBAR(0);
  compute(1);          // it=31

  // ---- LDS-repacked epilogue: scatter C-layout -> Shm, full-line stores ----
  const float scale = (mode == 0) ? qscale : 1.0f;
  __syncthreads();
#pragma unroll
  for (int mi = 0; mi < 4; ++mi)
#pragma unroll
    for (int ni = 0; ni < 4; ++ni)
#pragma unroll
      for (int r = 0; r < 4; ++r) {
        int rl, cl;
        if (!vswap) {   // rows = m, cols = n
          rl = wm * 64 + mi * 16 + quad * 4 + r;
          cl = wn * 64 + ni * 16 + lane15;
        } else {        // rows = weight-col, cols = activation row (t)
          rl = wn * 64 + ni * 16 + quad * 4 + r;
          cl = wm * 64 + mi * 16 + lane15;
        }
        Shm[rl * 128 + (cl ^ ((rl & 3) << 4))] = f2bf(acc[mi][ni][r] * scale);
      }
  __syncthreads();
#pragma unroll
  for (int j = 0; j < 8; ++j) {
    int c = t + j * 256;             // 2048 chunks of 8 u16
    int row = c >> 4, ch = c & 15;
    short8 v = *(const short8*)&Shm[row * 128 + ((ch ^ ((row & 3) << 1)) << 3)];
    if (mode == 0)
      *(short8*)&qp[(size_t)(bm + row) * 1024 + bn + ch * 8] = v;
    else if (mode == 1)
      *(short8*)&kp[(size_t)(bm + row) * 1024 + bn + ch * 8] = v;
    else {
      int b = bm >> 11;
      *(short8*)&vt[(size_t)(b * 1024 + (bn - 1024) + row) * 2048 +
                    (bm & 2047) + ch * 8] = v;
    }
  }
}

// ====== output projection: 128x64, BK=32, 3-buf pipeline, repacked fp32 =====
__global__ __launch_bounds__(256, 4) void gemm_out(const u16* __restrict__ A,
                                                   const u16* __restrict__ Bt,
                                                   float* __restrict__ C) {
  __shared__ __align__(16) u16 Shm[18432];   // 36 KB: As 3*4096 | Bs 3*2048
  u16* As = Shm;
  u16* Bs = Shm + 12288;
  float* Shf = (float*)Shm;                  // epilogue: [128][64] fp32 (32 KB)
  const int t = threadIdx.x;
  const int w = t >> 6, l = t & 63;
  const int lane15 = l & 15, quad = l >> 4;
  const int wm = w >> 1, wn = w & 1;

  const int bid = blockIdx.x;                // 512 blocks
  const int xr = bid & 7, g = bid >> 3;      // g in [0,64)
  const int bx = 8 * (xr & 1) + g % 8;       // [0,16)
  const int by = 8 * (xr >> 1) + g / 8;      // [0,32)
  const int bm = by * 128, bn = bx * 64;

  const int srow = t >> 2;
  const int scol = (((t & 3) ^ swz4(srow)) << 3);
  const u16* ag0 = A + (size_t)(bm + srow) * 1024 + scol;
  const u16* ag1 = ag0 + (size_t)64 * 1024;
  const u16* bg0 = Bt + (size_t)(bn + srow) * 1024 + scol;

  int afo[4], bfo[2];
#pragma unroll
  for (int mi = 0; mi < 4; ++mi) {
    int row = wm * 64 + mi * 16 + lane15;
    afo[mi] = row * 32 + ((quad ^ swz4(row)) << 3);
  }
#pragma unroll
  for (int ni = 0; ni < 2; ++ni) {
    int row = wn * 32 + ni * 16 + lane15;
    bfo[ni] = row * 32 + ((quad ^ swz4(row)) << 3);
  }

  floatx4 acc[4][2] = {};

  auto stage = [&](int kt, int buf) {
    gld16(ag0 + kt, &As[buf * 4096 + t * 8]);
    gld16(ag1 + kt, &As[buf * 4096 + 2048 + t * 8]);
    gld16(bg0 + kt, &Bs[buf * 2048 + t * 8]);
  };
  auto compute = [&](int buf) {
    short8 af[4], bf[2];
#pragma unroll
    for (int mi = 0; mi < 4; ++mi) af[mi] = *(const short8*)&As[buf * 4096 + afo[mi]];
#pragma unroll
    for (int ni = 0; ni < 2; ++ni) bf[ni] = *(const short8*)&Bs[buf * 2048 + bfo[ni]];
#pragma unroll
    for (int mi = 0; mi < 4; ++mi)
#pragma unroll
      for (int ni = 0; ni < 2; ++ni)
        acc[mi][ni] = __builtin_amdgcn_mfma_f32_16x16x32_bf16(af[mi], bf[ni],
                                                              acc[mi][ni], 0, 0, 0);
  };

  stage(0, 0);
  stage(32, 1);
#pragma unroll
  for (int it = 0; it < 30; ++it) {
    WBAR(3);
    compute(it % 3);
    stage((it + 2) * 32, (it + 2) % 3);
  }
  WBAR(3);
  compute(0);          // it=30
  WBAR(0);
  compute(1);          // it=31

  __syncthreads();
#pragma unroll
  for (int mi = 0; mi < 4; ++mi)
#pragma unroll
    for (int ni = 0; ni < 2; ++ni)
#pragma unroll
      for (int r = 0; r < 4; ++r) {
        int rl = wm * 64 + mi * 16 + quad * 4 + r;
        int cl = wn * 32 + ni * 16 + lane15;
        Shf[rl * 64 + (cl ^ ((rl & 3) << 4))] = acc[mi][ni][r];
      }
  __syncthreads();
#pragma unroll
  for (int j = 0; j < 8; ++j) {
    int c = t + j * 256;             // 2048 chunks of float4
    int row = c >> 4, ch = c & 15;
    float4v v = *(const float4v*)&Shf[row * 64 + ((ch ^ ((row & 3) << 2)) << 2)];
    *(float4v*)&C[(size_t)(bm + row) * 1024 + bn + ch * 4] = v;
  }
}

// ---------------- flash attention (S^T layout, BM=128, 8 waves, dbuf x2) ----
__global__ __launch_bounds__(512) void attn_kern(const u16* __restrict__ Q,
                                                 const u16* __restrict__ KP,
                                                 const u16* __restrict__ VT,
                                                 u16* __restrict__ Y) {
  __shared__ __align__(16) u16 Ks[2 * 4096];
  __shared__ __align__(16) u16 VTs[2 * 4096];
  __shared__ __align__(16) u16 Ps[8192];
  const int t = threadIdx.x, w = t >> 6, l = t & 63;
  const int lane15 = l & 15, quad = l >> 4;

  const int bid = blockIdx.x;
  const int xr = bid & 7, g = bid >> 3;     // g in [0,64)
  const int bxt = 8 * (xr & 1) + g % 8;     // [0,16)
  const int bh = 8 * (xr >> 1) + g / 8;     // [0,32)
  const int b = bh >> 4, h = bh & 15;
  const int qrow0 = b * 2048 + bxt * 128;
  const int xm = lane15 & 7;

  short8 qf[2];
#pragma unroll
  for (int ks = 0; ks < 2; ++ks)
    qf[ks] = *(const short8*)&Q[(size_t)(qrow0 + w * 16 + lane15) * 1024 +
                                h * 64 + ks * 32 + quad * 8];

  const short8 vones = {0x3F80, 0x3F80, 0x3F80, 0x3F80,
                        0x3F80, 0x3F80, 0x3F80, 0x3F80};

  floatx4 yacc[4] = {};
  floatx4 lacc = {};

  const int srow = t >> 3;                          // 0..63
  const int scol = (((t & 7) ^ (srow & 7)) << 3);
  const u16* kg = KP + (size_t)(b * 2048 + srow) * 1024 + h * 64 + scol;
  const u16* vg = VT + (size_t)(bh * 64 + srow) * 2048 + scol;

  const int prow = (w * 16 + lane15) * 64;
  int kfo[2][4], vfo[2][4], pwo[4], pro[2];
#pragma unroll
  for (int ks = 0; ks < 2; ++ks)
#pragma unroll
    for (int ti = 0; ti < 4; ++ti)
      kfo[ks][ti] = (ti * 16 + lane15) * 64 + (((ks * 4 + quad) ^ xm) << 3);
#pragma unroll
  for (int ts = 0; ts < 2; ++ts) {
#pragma unroll
    for (int ni = 0; ni < 4; ++ni)
      vfo[ts][ni] = (ni * 16 + lane15) * 64 + (((ts * 4 + quad) ^ xm) << 3);
    pro[ts] = prow + (((ts * 4 + quad) ^ xm) << 3);
  }
#pragma unroll
  for (int ti = 0; ti < 4; ++ti)
    pwo[ti] = prow + (((ti * 2 + (quad >> 1)) ^ xm) << 3) + ((quad & 1) << 2);

  auto stage = [&](int t0n, int buf) {
    gld16(kg + (size_t)t0n * 1024, &Ks[buf + t * 8]);
    gld16(vg + t0n, &VTs[buf + t * 8]);
  };
  auto compute = [&](int buf) {
    floatx4 sacc[4] = {};
#pragma unroll
    for (int ks = 0; ks < 2; ++ks)
#pragma unroll
      for (int ti = 0; ti < 4; ++ti) {
        short8 kf = *(const short8*)&Ks[buf + kfo[ks][ti]];
        sacc[ti] = __builtin_amdgcn_mfma_f32_16x16x32_bf16(kf, qf[ks], sacc[ti], 0, 0, 0);
      }
#pragma unroll
    for (int ti = 0; ti < 4; ++ti) {
      float p0 = fast_exp2(sacc[ti][0]);
      float p1 = fast_exp2(sacc[ti][1]);
      float p2 = fast_exp2(sacc[ti][2]);
      float p3 = fast_exp2(sacc[ti][3]);
      uint2 pk;
      pk.x = pack_bf2(p0, p1);
      pk.y = pack_bf2(p2, p3);
      *(uint2*)&Ps[pwo[ti]] = pk;
    }
#pragma unroll
    for (int ts = 0; ts < 2; ++ts) {
      short8 pf = *(const short8*)&Ps[pro[ts]];
      lacc = __builtin_amdgcn_mfma_f32_16x16x32_bf16(pf, vones, lacc, 0, 0, 0);
#pragma unroll
      for (int ni = 0; ni < 4; ++ni) {
        short8 vf = *(const short8*)&VTs[buf + vfo[ts][ni]];
        yacc[ni] = __builtin_amdgcn_mfma_f32_16x16x32_bf16(pf, vf, yacc[ni], 0, 0, 0);
      }
    }
  };

  stage(0, 0);
  __syncthreads();
  for (int t0 = 0; t0 < 2048; t0 += 128) {
    if (t0 + 64 < 2048) stage(t0 + 64, 4096);
    compute(0);
    __syncthreads();
    if (t0 + 128 < 2048) stage(t0 + 128, 0);
    compute(4096);
    __syncthreads();
  }

#pragma unroll
  for (int r = 0; r < 4; ++r) {
    float linv = 1.0f / lacc[r];
    int row = qrow0 + w * 16 + quad * 4 + r;
#pragma unroll
    for (int ni = 0; ni < 4; ++ni)
      Y[(size_t)row * 1024 + h * 64 + ni * 16 + lane15] = f2bf(yacc[ni][r] * linv);
  }
}

// ---------------- launch ----------------
extern "C" void kernel_launch(void* const* d_in, const int* in_sizes, int n_in,
                              void* d_out, int out_size, void* d_ws, size_t ws_size,
                              hipStream_t stream) {
  const float* query = (const float*)d_in[0];
  const float* key_value = (const float*)d_in[1];
  const float* Wq = (const float*)d_in[2];
  const float* Wkv = (const float*)d_in[3];
  const float* Wc = (const float*)d_in[4];
  float* out = (float*)d_out;

  const size_t MB = 1024 * 1024;
  char* ws = (char*)d_ws;
  u16* qin  = (u16*)(ws + 0 * MB);
  u16* kvin = (u16*)(ws + 8 * MB);
  u16* Wqt  = (u16*)(ws + 16 * MB);
  u16* Wkvt = (u16*)(ws + 18 * MB);
  u16* Wct  = (u16*)(ws + 22 * MB);
  u16* qp   = (u16*)(ws + 24 * MB);
  u16* kp   = (u16*)(ws + 32 * MB);
  u16* vt   = (u16*)(ws + 40 * MB);
  u16* y    = (u16*)(ws + 48 * MB);

  prep<<<dim3(12288), dim3(256), 0, stream>>>(query, key_value, Wq, Wkv, Wc,
                                              qin, kvin, Wqt, Wkvt, Wct);
  const float qscale = 0.125f * 1.4426950408889634f;
  gemm_qkv<<<dim3(768), dim3(256), 0, stream>>>(qin, kvin, Wqt, Wkvt,
                                                qp, kp, vt, qscale);
  attn_kern<<<dim3(512), dim3(512), 0, stream>>>(qp, kp, vt, y);
  gemm_out<<<dim3(512), dim3(256), 0, stream>>>(y, Wct, out);
}

// Round 12
// 187.522 us; speedup vs baseline: 1.7941x; 1.0111x over previous
//
#include <hip/hip_runtime.h>
#include <hip/hip_bf16.h>

// CrossAttention: out = softmax((X Wq)(KV Wk)^T / 8) (KV Wv) Wc
// B=2 S=T=2048 H=1024 nh=16 hd=64
// R12: port the R11 AITER-style pipeline to attn_kern — 3-buf K/V staging,
//      prefetch distance 2, `s_waitcnt vmcnt(2); s_barrier` (full drain only
//      at the final tile). 10x3-phase literal-buffer loop. LDS 64 KB = the
//      grid-limited 2 blocks/CU. gemm_qkv/gemm_out/prep frozen from R11.

typedef unsigned short u16;
typedef __attribute__((ext_vector_type(4))) float float4v;
typedef __attribute__((ext_vector_type(4))) unsigned short u16x4;
typedef __attribute__((ext_vector_type(8))) short short8;
typedef __attribute__((ext_vector_type(4))) float floatx4;

__device__ __forceinline__ u16 f2bf(float f) {
  unsigned u = __float_as_uint(f);
  u += 0x7fffu + ((u >> 16) & 1u);   // RNE
  return (u16)(u >> 16);
}

__device__ __forceinline__ float fast_exp2(float x) {
#if __has_builtin(__builtin_amdgcn_exp2f)
  return __builtin_amdgcn_exp2f(x);
#else
  return exp2f(x);
#endif
}

__device__ __forceinline__ unsigned pack_bf2(float a, float b) {
#if __has_builtin(__builtin_amdgcn_cvt_pk_bf16_f32)
  auto r = __builtin_amdgcn_cvt_pk_bf16_f32(a, b);
  unsigned u;
  __builtin_memcpy(&u, &r, 4);
  return u;
#else
  unsigned ua = __float_as_uint(a) + 0x7fffu + ((__float_as_uint(a) >> 16) & 1u);
  unsigned ub = __float_as_uint(b) + 0x7fffu + ((__float_as_uint(b) >> 16) & 1u);
  return __builtin_amdgcn_perm(ub, ua, 0x07060302u);
#endif
}

__device__ __forceinline__ void gld16(const void* g, void* l) {
  __builtin_amdgcn_global_load_lds(
      (const __attribute__((address_space(1))) void*)g,
      (__attribute__((address_space(3))) void*)l, 16, 0, 0);
}

// barrier that leaves the newest N vector-loads in flight
#define WBAR(N) asm volatile("s_waitcnt vmcnt(" #N ") lgkmcnt(0)\n\ts_barrier" ::: "memory")

// row swizzle for 32-elem (4-chunk) LDS rows
__device__ __forceinline__ int swz4(int r) { return (r & 3) ^ ((r >> 2) & 3); }

// ---------------- prep: activation cvt + weight transposes, one launch ------
__global__ void prep(const float* __restrict__ X, const float* __restrict__ KV,
                     const float* __restrict__ Wq, const float* __restrict__ Wkv,
                     const float* __restrict__ Wc,
                     u16* __restrict__ qin, u16* __restrict__ kvin,
                     u16* __restrict__ Wqt, u16* __restrict__ Wkvt,
                     u16* __restrict__ Wct) {
  __shared__ float tile[32][33];
  const int bid = blockIdx.x, t = threadIdx.x;
  if (bid < 8192) {
    const float* src = bid < 4096 ? X : KV;
    u16* dst = bid < 4096 ? qin : kvin;
    int i = (bid & 4095) * 256 + t;
    float4v v = ((const float4v*)src)[i];
    u16x4 o;
    o.x = f2bf(v.x); o.y = f2bf(v.y); o.z = f2bf(v.z); o.w = f2bf(v.w);
    ((u16x4*)dst)[i] = o;
  } else {
    int r = bid - 8192;
    const float* in;
    u16* out;
    int C, bx, by;
    if (r < 1024)      { in = Wq;  out = Wqt;  C = 1024; bx = r & 31; by = r >> 5; }
    else if (r < 3072) { r -= 1024; in = Wkv; out = Wkvt; C = 2048; bx = r & 63; by = r >> 6; }
    else               { r -= 3072; in = Wc;  out = Wct;  C = 1024; bx = r & 31; by = r >> 5; }
    const int tx = t & 31, ty = t >> 5;   // 32 x 8
#pragma unroll
    for (int i = 0; i < 32; i += 8)
      tile[ty + i][tx] = in[(size_t)(by * 32 + ty + i) * C + bx * 32 + tx];
    __syncthreads();
#pragma unroll
    for (int i = 0; i < 32; i += 8)
      out[(size_t)(bx * 32 + ty + i) * 1024 + by * 32 + tx] = f2bf(tile[tx][ty + i]);
  }
}

// ======= fused q/k/v projection (bf16), 128x128, BK=32, 3-buf pipeline ======
__global__ __launch_bounds__(256, 3) void gemm_qkv(const u16* __restrict__ qin,
                                                   const u16* __restrict__ kvin,
                                                   const u16* __restrict__ Wqt,
                                                   const u16* __restrict__ Wkvt,
                                                   u16* __restrict__ qp,
                                                   u16* __restrict__ kp,
                                                   u16* __restrict__ vt,
                                                   float qscale) {
  __shared__ __align__(16) u16 Shm[24576];   // 48 KB: As 3*4096 | Bs 3*4096
  u16* As = Shm;
  u16* Bs = Shm + 12288;
  const int t = threadIdx.x;
  const int w = t >> 6, l = t & 63;
  const int lane15 = l & 15, quad = l >> 4;
  const int wm = w >> 1, wn = w & 1;

  const int bid = blockIdx.x;
  const int xr = bid & 7, g = bid >> 3;          // g in [0,96)
  const int bx = 12 * (xr & 1) + g % 12;
  const int by = 8 * (xr >> 1) + g / 12;
  const int bm = by * 128;

  const int mode = bx >> 3;                 // 0=q 1=k 2=v
  const u16* A = (mode == 0) ? qin : kvin;
  const u16* Bt = (mode == 0) ? Wqt : Wkvt;
  const int bn = (mode == 2) ? 1024 + (bx - 16) * 128 : (bx & 7) * 128;

  const int srow = t >> 2;                            // 0..63
  const int scol = (((t & 3) ^ swz4(srow)) << 3);
  const u16* ag0 = A + (size_t)(bm + srow) * 1024 + scol;
  const u16* ag1 = ag0 + (size_t)64 * 1024;
  const u16* bg0 = Bt + (size_t)(bn + srow) * 1024 + scol;
  const u16* bg1 = bg0 + (size_t)64 * 1024;

  int afo[4], bfo[4];
#pragma unroll
  for (int mi = 0; mi < 4; ++mi) {
    int row = wm * 64 + mi * 16 + lane15;
    afo[mi] = row * 32 + ((quad ^ swz4(row)) << 3);
  }
#pragma unroll
  for (int ni = 0; ni < 4; ++ni) {
    int row = wn * 64 + ni * 16 + lane15;
    bfo[ni] = row * 32 + ((quad ^ swz4(row)) << 3);
  }

  floatx4 acc[4][4] = {};
  const bool vswap = (mode == 2);

  auto stage = [&](int kt, int buf) {
    gld16(ag0 + kt, &As[buf * 4096 + t * 8]);
    gld16(ag1 + kt, &As[buf * 4096 + 2048 + t * 8]);
    gld16(bg0 + kt, &Bs[buf * 4096 + t * 8]);
    gld16(bg1 + kt, &Bs[buf * 4096 + 2048 + t * 8]);
  };
  auto compute = [&](int buf) {
    short8 af[4], bf[4];
#pragma unroll
    for (int mi = 0; mi < 4; ++mi) af[mi] = *(const short8*)&As[buf * 4096 + afo[mi]];
#pragma unroll
    for (int ni = 0; ni < 4; ++ni) bf[ni] = *(const short8*)&Bs[buf * 4096 + bfo[ni]];
    if (!vswap) {
#pragma unroll
      for (int mi = 0; mi < 4; ++mi)
#pragma unroll
        for (int ni = 0; ni < 4; ++ni)
          acc[mi][ni] = __builtin_amdgcn_mfma_f32_16x16x32_bf16(af[mi], bf[ni],
                                                                acc[mi][ni], 0, 0, 0);
    } else {
#pragma unroll
      for (int mi = 0; mi < 4; ++mi)
#pragma unroll
        for (int ni = 0; ni < 4; ++ni)
          acc[mi][ni] = __builtin_amdgcn_mfma_f32_16x16x32_bf16(bf[ni], af[mi],
                                                                acc[mi][ni], 0, 0, 0);
    }
  };

  stage(0, 0);
  stage(32, 1);
#pragma unroll
  for (int it = 0; it < 30; ++it) {
    WBAR(4);
    compute(it % 3);
    stage((it + 2) * 32, (it + 2) % 3);
  }
  WBAR(4);
  compute(0);          // it=30
  WBAR(0);
  compute(1);          // it=31

  const float scale = (mode == 0) ? qscale : 1.0f;
  __syncthreads();
#pragma unroll
  for (int mi = 0; mi < 4; ++mi)
#pragma unroll
    for (int ni = 0; ni < 4; ++ni)
#pragma unroll
      for (int r = 0; r < 4; ++r) {
        int rl, cl;
        if (!vswap) {
          rl = wm * 64 + mi * 16 + quad * 4 + r;
          cl = wn * 64 + ni * 16 + lane15;
        } else {
          rl = wn * 64 + ni * 16 + quad * 4 + r;
          cl = wm * 64 + mi * 16 + lane15;
        }
        Shm[rl * 128 + (cl ^ ((rl & 3) << 4))] = f2bf(acc[mi][ni][r] * scale);
      }
  __syncthreads();
#pragma unroll
  for (int j = 0; j < 8; ++j) {
    int c = t + j * 256;             // 2048 chunks of 8 u16
    int row = c >> 4, ch = c & 15;
    short8 v = *(const short8*)&Shm[row * 128 + ((ch ^ ((row & 3) << 1)) << 3)];
    if (mode == 0)
      *(short8*)&qp[(size_t)(bm + row) * 1024 + bn + ch * 8] = v;
    else if (mode == 1)
      *(short8*)&kp[(size_t)(bm + row) * 1024 + bn + ch * 8] = v;
    else {
      int b = bm >> 11;
      *(short8*)&vt[(size_t)(b * 1024 + (bn - 1024) + row) * 2048 +
                    (bm & 2047) + ch * 8] = v;
    }
  }
}

// ====== output projection: 128x64, BK=32, 3-buf pipeline, repacked fp32 =====
__global__ __launch_bounds__(256, 4) void gemm_out(const u16* __restrict__ A,
                                                   const u16* __restrict__ Bt,
                                                   float* __restrict__ C) {
  __shared__ __align__(16) u16 Shm[18432];   // 36 KB: As 3*4096 | Bs 3*2048
  u16* As = Shm;
  u16* Bs = Shm + 12288;
  float* Shf = (float*)Shm;
  const int t = threadIdx.x;
  const int w = t >> 6, l = t & 63;
  const int lane15 = l & 15, quad = l >> 4;
  const int wm = w >> 1, wn = w & 1;

  const int bid = blockIdx.x;                // 512 blocks
  const int xr = bid & 7, g = bid >> 3;
  const int bx = 8 * (xr & 1) + g % 8;
  const int by = 8 * (xr >> 1) + g / 8;
  const int bm = by * 128, bn = bx * 64;

  const int srow = t >> 2;
  const int scol = (((t & 3) ^ swz4(srow)) << 3);
  const u16* ag0 = A + (size_t)(bm + srow) * 1024 + scol;
  const u16* ag1 = ag0 + (size_t)64 * 1024;
  const u16* bg0 = Bt + (size_t)(bn + srow) * 1024 + scol;

  int afo[4], bfo[2];
#pragma unroll
  for (int mi = 0; mi < 4; ++mi) {
    int row = wm * 64 + mi * 16 + lane15;
    afo[mi] = row * 32 + ((quad ^ swz4(row)) << 3);
  }
#pragma unroll
  for (int ni = 0; ni < 2; ++ni) {
    int row = wn * 32 + ni * 16 + lane15;
    bfo[ni] = row * 32 + ((quad ^ swz4(row)) << 3);
  }

  floatx4 acc[4][2] = {};

  auto stage = [&](int kt, int buf) {
    gld16(ag0 + kt, &As[buf * 4096 + t * 8]);
    gld16(ag1 + kt, &As[buf * 4096 + 2048 + t * 8]);
    gld16(bg0 + kt, &Bs[buf * 2048 + t * 8]);
  };
  auto compute = [&](int buf) {
    short8 af[4], bf[2];
#pragma unroll
    for (int mi = 0; mi < 4; ++mi) af[mi] = *(const short8*)&As[buf * 4096 + afo[mi]];
#pragma unroll
    for (int ni = 0; ni < 2; ++ni) bf[ni] = *(const short8*)&Bs[buf * 2048 + bfo[ni]];
#pragma unroll
    for (int mi = 0; mi < 4; ++mi)
#pragma unroll
      for (int ni = 0; ni < 2; ++ni)
        acc[mi][ni] = __builtin_amdgcn_mfma_f32_16x16x32_bf16(af[mi], bf[ni],
                                                              acc[mi][ni], 0, 0, 0);
  };

  stage(0, 0);
  stage(32, 1);
#pragma unroll
  for (int it = 0; it < 30; ++it) {
    WBAR(3);
    compute(it % 3);
    stage((it + 2) * 32, (it + 2) % 3);
  }
  WBAR(3);
  compute(0);
  WBAR(0);
  compute(1);

  __syncthreads();
#pragma unroll
  for (int mi = 0; mi < 4; ++mi)
#pragma unroll
    for (int ni = 0; ni < 2; ++ni)
#pragma unroll
      for (int r = 0; r < 4; ++r) {
        int rl = wm * 64 + mi * 16 + quad * 4 + r;
        int cl = wn * 32 + ni * 16 + lane15;
        Shf[rl * 64 + (cl ^ ((rl & 3) << 4))] = acc[mi][ni][r];
      }
  __syncthreads();
#pragma unroll
  for (int j = 0; j < 8; ++j) {
    int c = t + j * 256;
    int row = c >> 4, ch = c & 15;
    float4v v = *(const float4v*)&Shf[row * 64 + ((ch ^ ((row & 3) << 2)) << 2)];
    *(float4v*)&C[(size_t)(bm + row) * 1024 + bn + ch * 4] = v;
  }
}

// ------- flash attention (S^T layout, BM=128, 8 waves, 3-buf pipeline) ------
// 32 K/V tiles of 64; prologue stages 0,1; 10 x 3-phase loop with literal
// buffers; vmcnt(2) barriers (full drain only for the last tile). Ps is
// wave-private (rows w*16..w*16+15) -> single buffer, no extra hazard.
__global__ __launch_bounds__(512) void attn_kern(const u16* __restrict__ Q,
                                                 const u16* __restrict__ KP,
                                                 const u16* __restrict__ VT,
                                                 u16* __restrict__ Y) {
  __shared__ __align__(16) u16 Ks[3 * 4096];    // [buf][t'][d], chunk^=(t'&7)
  __shared__ __align__(16) u16 VTs[3 * 4096];   // [buf][d][t'], chunk^=(d&7)
  __shared__ __align__(16) u16 Ps[8192];        // [m 0..127][t'], chunk^=(m&7)
  const int t = threadIdx.x, w = t >> 6, l = t & 63;
  const int lane15 = l & 15, quad = l >> 4;

  const int bid = blockIdx.x;
  const int xr = bid & 7, g = bid >> 3;     // g in [0,64)
  const int bxt = 8 * (xr & 1) + g % 8;     // [0,16)
  const int bh = 8 * (xr >> 1) + g / 8;     // [0,32)
  const int b = bh >> 4, h = bh & 15;
  const int qrow0 = b * 2048 + bxt * 128;
  const int xm = lane15 & 7;

  short8 qf[2];
#pragma unroll
  for (int ks = 0; ks < 2; ++ks)
    qf[ks] = *(const short8*)&Q[(size_t)(qrow0 + w * 16 + lane15) * 1024 +
                                h * 64 + ks * 32 + quad * 8];

  const short8 vones = {0x3F80, 0x3F80, 0x3F80, 0x3F80,
                        0x3F80, 0x3F80, 0x3F80, 0x3F80};

  floatx4 yacc[4] = {};
  floatx4 lacc = {};

  const int srow = t >> 3;                          // 0..63
  const int scol = (((t & 7) ^ (srow & 7)) << 3);
  const u16* kg = KP + (size_t)(b * 2048 + srow) * 1024 + h * 64 + scol;
  const u16* vg = VT + (size_t)(bh * 64 + srow) * 2048 + scol;

  const int prow = (w * 16 + lane15) * 64;
  int kfo[2][4], vfo[2][4], pwo[4], pro[2];
#pragma unroll
  for (int ks = 0; ks < 2; ++ks)
#pragma unroll
    for (int ti = 0; ti < 4; ++ti)
      kfo[ks][ti] = (ti * 16 + lane15) * 64 + (((ks * 4 + quad) ^ xm) << 3);
#pragma unroll
  for (int ts = 0; ts < 2; ++ts) {
#pragma unroll
    for (int ni = 0; ni < 4; ++ni)
      vfo[ts][ni] = (ni * 16 + lane15) * 64 + (((ts * 4 + quad) ^ xm) << 3);
    pro[ts] = prow + (((ts * 4 + quad) ^ xm) << 3);
  }
#pragma unroll
  for (int ti = 0; ti < 4; ++ti)
    pwo[ti] = prow + (((ti * 2 + (quad >> 1)) ^ xm) << 3) + ((quad & 1) << 2);

  auto stage = [&](int t0n, int buf) {
    gld16(kg + (size_t)t0n * 1024, &Ks[buf * 4096 + t * 8]);
    gld16(vg + t0n, &VTs[buf * 4096 + t * 8]);
  };
  auto compute = [&](int buf) {
    floatx4 sacc[4] = {};
#pragma unroll
    for (int ks = 0; ks < 2; ++ks)
#pragma unroll
      for (int ti = 0; ti < 4; ++ti) {
        short8 kf = *(const short8*)&Ks[buf * 4096 + kfo[ks][ti]];
        sacc[ti] = __builtin_amdgcn_mfma_f32_16x16x32_bf16(kf, qf[ks], sacc[ti], 0, 0, 0);
      }
#pragma unroll
    for (int ti = 0; ti < 4; ++ti) {
      float p0 = fast_exp2(sacc[ti][0]);
      float p1 = fast_exp2(sacc[ti][1]);
      float p2 = fast_exp2(sacc[ti][2]);
      float p3 = fast_exp2(sacc[ti][3]);
      uint2 pk;
      pk.x = pack_bf2(p0, p1);
      pk.y = pack_bf2(p2, p3);
      *(uint2*)&Ps[pwo[ti]] = pk;
    }
#pragma unroll
    for (int ts = 0; ts < 2; ++ts) {
      short8 pf = *(const short8*)&Ps[pro[ts]];
      lacc = __builtin_amdgcn_mfma_f32_16x16x32_bf16(pf, vones, lacc, 0, 0, 0);
#pragma unroll
      for (int ni = 0; ni < 4; ++ni) {
        short8 vf = *(const short8*)&VTs[buf * 4096 + vfo[ts][ni]];
        yacc[ni] = __builtin_amdgcn_mfma_f32_16x16x32_bf16(pf, vf, yacc[ni], 0, 0, 0);
      }
    }
  };

  // 3-buf pipeline: tile i lives in buf i%3, staged 2 phases ahead.
  stage(0, 0);
  stage(64, 1);
  for (int i = 0; i < 10; ++i) {
    const int base = i * 192;
    WBAR(2);
    compute(0);
    stage(base + 128, 2);
    WBAR(2);
    compute(1);
    stage(base + 192, 0);
    WBAR(2);
    compute(2);
    stage(base + 256, 1);
  }
  WBAR(2);
  compute(0);          // tile 30
  WBAR(0);
  compute(1);          // tile 31

  // epilogue: y = yacc / l ; lacc C-layout row m=quad*4+r matches store rows
#pragma unroll
  for (int r = 0; r < 4; ++r) {
    float linv = 1.0f / lacc[r];
    int row = qrow0 + w * 16 + quad * 4 + r;
#pragma unroll
    for (int ni = 0; ni < 4; ++ni)
      Y[(size_t)row * 1024 + h * 64 + ni * 16 + lane15] = f2bf(yacc[ni][r] * linv);
  }
}

// ---------------- launch ----------------
extern "C" void kernel_launch(void* const* d_in, const int* in_sizes, int n_in,
                              void* d_out, int out_size, void* d_ws, size_t ws_size,
                              hipStream_t stream) {
  const float* query = (const float*)d_in[0];
  const float* key_value = (const float*)d_in[1];
  const float* Wq = (const float*)d_in[2];
  const float* Wkv = (const float*)d_in[3];
  const float* Wc = (const float*)d_in[4];
  float* out = (float*)d_out;

  const size_t MB = 1024 * 1024;
  char* ws = (char*)d_ws;
  u16* qin  = (u16*)(ws + 0 * MB);
  u16* kvin = (u16*)(ws + 8 * MB);
  u16* Wqt  = (u16*)(ws + 16 * MB);
  u16* Wkvt = (u16*)(ws + 18 * MB);
  u16* Wct  = (u16*)(ws + 22 * MB);
  u16* qp   = (u16*)(ws + 24 * MB);
  u16* kp   = (u16*)(ws + 32 * MB);
  u16* vt   = (u16*)(ws + 40 * MB);
  u16* y    = (u16*)(ws + 48 * MB);

  prep<<<dim3(12288), dim3(256), 0, stream>>>(query, key_value, Wq, Wkv, Wc,
                                              qin, kvin, Wqt, Wkvt, Wct);
  const float qscale = 0.125f * 1.4426950408889634f;
  gemm_qkv<<<dim3(768), dim3(256), 0, stream>>>(qin, kvin, Wqt, Wkvt,
                                                qp, kp, vt, qscale);
  attn_kern<<<dim3(512), dim3(512), 0, stream>>>(qp, kp, vt, y);
  gemm_out<<<dim3(512), dim3(256), 0, stream>>>(y, Wct, out);
}

// Round 13
// 182.527 us; speedup vs baseline: 1.8432x; 1.0274x over previous
//
#include <hip/hip_runtime.h>
#include <hip/hip_bf16.h>

// CrossAttention: out = softmax((X Wq)(KV Wk)^T / 8) (KV Wv) Wc
// B=2 S=T=2048 H=1024 nh=16 hd=64
// R13: P-matrix LDS roundtrip eliminated via k-permutation: PV sums over a
//      permuted t'-order pi(32a+16b+4q+r)=32a+8q+4b+r so the PV A-fragment
//      equals the lane's own sacc registers (exp+pack, no cross-lane, no Ps).
//      V is stored pre-permuted by gemm_qkv's vswap epilogue (free).
//      attn LDS 64->48 KB. gemm_qkv loop / gemm_out / prep frozen from R12.

typedef unsigned short u16;
typedef __attribute__((ext_vector_type(4))) float float4v;
typedef __attribute__((ext_vector_type(4))) unsigned short u16x4;
typedef __attribute__((ext_vector_type(8))) short short8;
typedef __attribute__((ext_vector_type(4))) float floatx4;

__device__ __forceinline__ u16 f2bf(float f) {
  unsigned u = __float_as_uint(f);
  u += 0x7fffu + ((u >> 16) & 1u);   // RNE
  return (u16)(u >> 16);
}

__device__ __forceinline__ float fast_exp2(float x) {
#if __has_builtin(__builtin_amdgcn_exp2f)
  return __builtin_amdgcn_exp2f(x);
#else
  return exp2f(x);
#endif
}

__device__ __forceinline__ unsigned pack_bf2(float a, float b) {
#if __has_builtin(__builtin_amdgcn_cvt_pk_bf16_f32)
  auto r = __builtin_amdgcn_cvt_pk_bf16_f32(a, b);
  unsigned u;
  __builtin_memcpy(&u, &r, 4);
  return u;
#else
  unsigned ua = __float_as_uint(a) + 0x7fffu + ((__float_as_uint(a) >> 16) & 1u);
  unsigned ub = __float_as_uint(b) + 0x7fffu + ((__float_as_uint(b) >> 16) & 1u);
  return __builtin_amdgcn_perm(ub, ua, 0x07060302u);
#endif
}

__device__ __forceinline__ void gld16(const void* g, void* l) {
  __builtin_amdgcn_global_load_lds(
      (const __attribute__((address_space(1))) void*)g,
      (__attribute__((address_space(3))) void*)l, 16, 0, 0);
}

// barrier that leaves the newest N vector-loads in flight
#define WBAR(N) asm volatile("s_waitcnt vmcnt(" #N ") lgkmcnt(0)\n\ts_barrier" ::: "memory")

// row swizzle for 32-elem (4-chunk) LDS rows
__device__ __forceinline__ int swz4(int r) { return (r & 3) ^ ((r >> 2) & 3); }

// pi-permutation within a 64-block of t: x = 32a+16b+4q+r -> 32a+8q+4b+r
__device__ __forceinline__ int perm64(int x) {
  return (x & 32) | ((x & 12) << 1) | ((x & 16) >> 2) | (x & 3);
}

// ---------------- prep: activation cvt + weight transposes, one launch ------
__global__ void prep(const float* __restrict__ X, const float* __restrict__ KV,
                     const float* __restrict__ Wq, const float* __restrict__ Wkv,
                     const float* __restrict__ Wc,
                     u16* __restrict__ qin, u16* __restrict__ kvin,
                     u16* __restrict__ Wqt, u16* __restrict__ Wkvt,
                     u16* __restrict__ Wct) {
  __shared__ float tile[32][33];
  const int bid = blockIdx.x, t = threadIdx.x;
  if (bid < 8192) {
    const float* src = bid < 4096 ? X : KV;
    u16* dst = bid < 4096 ? qin : kvin;
    int i = (bid & 4095) * 256 + t;
    float4v v = ((const float4v*)src)[i];
    u16x4 o;
    o.x = f2bf(v.x); o.y = f2bf(v.y); o.z = f2bf(v.z); o.w = f2bf(v.w);
    ((u16x4*)dst)[i] = o;
  } else {
    int r = bid - 8192;
    const float* in;
    u16* out;
    int C, bx, by;
    if (r < 1024)      { in = Wq;  out = Wqt;  C = 1024; bx = r & 31; by = r >> 5; }
    else if (r < 3072) { r -= 1024; in = Wkv; out = Wkvt; C = 2048; bx = r & 63; by = r >> 6; }
    else               { r -= 3072; in = Wc;  out = Wct;  C = 1024; bx = r & 31; by = r >> 5; }
    const int tx = t & 31, ty = t >> 5;   // 32 x 8
#pragma unroll
    for (int i = 0; i < 32; i += 8)
      tile[ty + i][tx] = in[(size_t)(by * 32 + ty + i) * C + bx * 32 + tx];
    __syncthreads();
#pragma unroll
    for (int i = 0; i < 32; i += 8)
      out[(size_t)(bx * 32 + ty + i) * 1024 + by * 32 + tx] = f2bf(tile[tx][ty + i]);
  }
}

// ======= fused q/k/v projection (bf16), 128x128, BK=32, 3-buf pipeline ======
__global__ __launch_bounds__(256, 3) void gemm_qkv(const u16* __restrict__ qin,
                                                   const u16* __restrict__ kvin,
                                                   const u16* __restrict__ Wqt,
                                                   const u16* __restrict__ Wkvt,
                                                   u16* __restrict__ qp,
                                                   u16* __restrict__ kp,
                                                   u16* __restrict__ vt,
                                                   float qscale) {
  __shared__ __align__(16) u16 Shm[24576];   // 48 KB: As 3*4096 | Bs 3*4096
  u16* As = Shm;
  u16* Bs = Shm + 12288;
  const int t = threadIdx.x;
  const int w = t >> 6, l = t & 63;
  const int lane15 = l & 15, quad = l >> 4;
  const int wm = w >> 1, wn = w & 1;

  const int bid = blockIdx.x;
  const int xr = bid & 7, g = bid >> 3;          // g in [0,96)
  const int bx = 12 * (xr & 1) + g % 12;
  const int by = 8 * (xr >> 1) + g / 12;
  const int bm = by * 128;

  const int mode = bx >> 3;                 // 0=q 1=k 2=v
  const u16* A = (mode == 0) ? qin : kvin;
  const u16* Bt = (mode == 0) ? Wqt : Wkvt;
  const int bn = (mode == 2) ? 1024 + (bx - 16) * 128 : (bx & 7) * 128;

  const int srow = t >> 2;                            // 0..63
  const int scol = (((t & 3) ^ swz4(srow)) << 3);
  const u16* ag0 = A + (size_t)(bm + srow) * 1024 + scol;
  const u16* ag1 = ag0 + (size_t)64 * 1024;
  const u16* bg0 = Bt + (size_t)(bn + srow) * 1024 + scol;
  const u16* bg1 = bg0 + (size_t)64 * 1024;

  int afo[4], bfo[4];
#pragma unroll
  for (int mi = 0; mi < 4; ++mi) {
    int row = wm * 64 + mi * 16 + lane15;
    afo[mi] = row * 32 + ((quad ^ swz4(row)) << 3);
  }
#pragma unroll
  for (int ni = 0; ni < 4; ++ni) {
    int row = wn * 64 + ni * 16 + lane15;
    bfo[ni] = row * 32 + ((quad ^ swz4(row)) << 3);
  }

  floatx4 acc[4][4] = {};
  const bool vswap = (mode == 2);

  auto stage = [&](int kt, int buf) {
    gld16(ag0 + kt, &As[buf * 4096 + t * 8]);
    gld16(ag1 + kt, &As[buf * 4096 + 2048 + t * 8]);
    gld16(bg0 + kt, &Bs[buf * 4096 + t * 8]);
    gld16(bg1 + kt, &Bs[buf * 4096 + 2048 + t * 8]);
  };
  auto compute = [&](int buf) {
    short8 af[4], bf[4];
#pragma unroll
    for (int mi = 0; mi < 4; ++mi) af[mi] = *(const short8*)&As[buf * 4096 + afo[mi]];
#pragma unroll
    for (int ni = 0; ni < 4; ++ni) bf[ni] = *(const short8*)&Bs[buf * 4096 + bfo[ni]];
    if (!vswap) {
#pragma unroll
      for (int mi = 0; mi < 4; ++mi)
#pragma unroll
        for (int ni = 0; ni < 4; ++ni)
          acc[mi][ni] = __builtin_amdgcn_mfma_f32_16x16x32_bf16(af[mi], bf[ni],
                                                                acc[mi][ni], 0, 0, 0);
    } else {
#pragma unroll
      for (int mi = 0; mi < 4; ++mi)
#pragma unroll
        for (int ni = 0; ni < 4; ++ni)
          acc[mi][ni] = __builtin_amdgcn_mfma_f32_16x16x32_bf16(bf[ni], af[mi],
                                                                acc[mi][ni], 0, 0, 0);
    }
  };

  stage(0, 0);
  stage(32, 1);
#pragma unroll
  for (int it = 0; it < 30; ++it) {
    WBAR(4);
    compute(it % 3);
    stage((it + 2) * 32, (it + 2) % 3);
  }
  WBAR(4);
  compute(0);          // it=30
  WBAR(0);
  compute(1);          // it=31

  const float scale = (mode == 0) ? qscale : 1.0f;
  __syncthreads();
#pragma unroll
  for (int mi = 0; mi < 4; ++mi)
#pragma unroll
    for (int ni = 0; ni < 4; ++ni)
#pragma unroll
      for (int r = 0; r < 4; ++r) {
        int rl, cl;
        if (!vswap) {
          rl = wm * 64 + mi * 16 + quad * 4 + r;
          cl = wn * 64 + ni * 16 + lane15;
        } else {
          // rows = weight-col (d), cols = activation row (t), with the
          // pi-permutation applied within each 64-block of t so attn's PV
          // A-fragment is lane-local (R13).
          rl = wn * 64 + ni * 16 + quad * 4 + r;
          int clr = wm * 64 + mi * 16 + lane15;
          cl = (clr & 64) | perm64(clr & 63);
        }
        Shm[rl * 128 + (cl ^ ((rl & 3) << 4))] = f2bf(acc[mi][ni][r] * scale);
      }
  __syncthreads();
#pragma unroll
  for (int j = 0; j < 8; ++j) {
    int c = t + j * 256;             // 2048 chunks of 8 u16
    int row = c >> 4, ch = c & 15;
    short8 v = *(const short8*)&Shm[row * 128 + ((ch ^ ((row & 3) << 1)) << 3)];
    if (mode == 0)
      *(short8*)&qp[(size_t)(bm + row) * 1024 + bn + ch * 8] = v;
    else if (mode == 1)
      *(short8*)&kp[(size_t)(bm + row) * 1024 + bn + ch * 8] = v;
    else {
      int b = bm >> 11;
      *(short8*)&vt[(size_t)(b * 1024 + (bn - 1024) + row) * 2048 +
                    (bm & 2047) + ch * 8] = v;
    }
  }
}

// ====== output projection: 128x64, BK=32, 3-buf pipeline, repacked fp32 =====
__global__ __launch_bounds__(256, 4) void gemm_out(const u16* __restrict__ A,
                                                   const u16* __restrict__ Bt,
                                                   float* __restrict__ C) {
  __shared__ __align__(16) u16 Shm[18432];   // 36 KB: As 3*4096 | Bs 3*2048
  u16* As = Shm;
  u16* Bs = Shm + 12288;
  float* Shf = (float*)Shm;
  const int t = threadIdx.x;
  const int w = t >> 6, l = t & 63;
  const int lane15 = l & 15, quad = l >> 4;
  const int wm = w >> 1, wn = w & 1;

  const int bid = blockIdx.x;                // 512 blocks
  const int xr = bid & 7, g = bid >> 3;
  const int bx = 8 * (xr & 1) + g % 8;
  const int by = 8 * (xr >> 1) + g / 8;
  const int bm = by * 128, bn = bx * 64;

  const int srow = t >> 2;
  const int scol = (((t & 3) ^ swz4(srow)) << 3);
  const u16* ag0 = A + (size_t)(bm + srow) * 1024 + scol;
  const u16* ag1 = ag0 + (size_t)64 * 1024;
  const u16* bg0 = Bt + (size_t)(bn + srow) * 1024 + scol;

  int afo[4], bfo[2];
#pragma unroll
  for (int mi = 0; mi < 4; ++mi) {
    int row = wm * 64 + mi * 16 + lane15;
    afo[mi] = row * 32 + ((quad ^ swz4(row)) << 3);
  }
#pragma unroll
  for (int ni = 0; ni < 2; ++ni) {
    int row = wn * 32 + ni * 16 + lane15;
    bfo[ni] = row * 32 + ((quad ^ swz4(row)) << 3);
  }

  floatx4 acc[4][2] = {};

  auto stage = [&](int kt, int buf) {
    gld16(ag0 + kt, &As[buf * 4096 + t * 8]);
    gld16(ag1 + kt, &As[buf * 4096 + 2048 + t * 8]);
    gld16(bg0 + kt, &Bs[buf * 2048 + t * 8]);
  };
  auto compute = [&](int buf) {
    short8 af[4], bf[2];
#pragma unroll
    for (int mi = 0; mi < 4; ++mi) af[mi] = *(const short8*)&As[buf * 4096 + afo[mi]];
#pragma unroll
    for (int ni = 0; ni < 2; ++ni) bf[ni] = *(const short8*)&Bs[buf * 2048 + bfo[ni]];
#pragma unroll
    for (int mi = 0; mi < 4; ++mi)
#pragma unroll
      for (int ni = 0; ni < 2; ++ni)
        acc[mi][ni] = __builtin_amdgcn_mfma_f32_16x16x32_bf16(af[mi], bf[ni],
                                                              acc[mi][ni], 0, 0, 0);
  };

  stage(0, 0);
  stage(32, 1);
#pragma unroll
  for (int it = 0; it < 30; ++it) {
    WBAR(3);
    compute(it % 3);
    stage((it + 2) * 32, (it + 2) % 3);
  }
  WBAR(3);
  compute(0);
  WBAR(0);
  compute(1);

  __syncthreads();
#pragma unroll
  for (int mi = 0; mi < 4; ++mi)
#pragma unroll
    for (int ni = 0; ni < 2; ++ni)
#pragma unroll
      for (int r = 0; r < 4; ++r) {
        int rl = wm * 64 + mi * 16 + quad * 4 + r;
        int cl = wn * 32 + ni * 16 + lane15;
        Shf[rl * 64 + (cl ^ ((rl & 3) << 4))] = acc[mi][ni][r];
      }
  __syncthreads();
#pragma unroll
  for (int j = 0; j < 8; ++j) {
    int c = t + j * 256;
    int row = c >> 4, ch = c & 15;
    float4v v = *(const float4v*)&Shf[row * 64 + ((ch ^ ((row & 3) << 2)) << 2)];
    *(float4v*)&C[(size_t)(bm + row) * 1024 + bn + ch * 4] = v;
  }
}

// ------- flash attention (S^T layout, BM=128, 8 waves, 3-buf, no Ps) --------
// V comes pre-permuted (pi within 64-blocks of t), so the PV A-fragment is
// built lane-locally from sacc: pf[j<4]=exp(sacc[2ts][j]), pf[j>=4]=
// exp(sacc[2ts+1][j-4]). No P LDS roundtrip. l via ones-MFMA (C-layout).
__global__ __launch_bounds__(512) void attn_kern(const u16* __restrict__ Q,
                                                 const u16* __restrict__ KP,
                                                 const u16* __restrict__ VT,
                                                 u16* __restrict__ Y) {
  __shared__ __align__(16) u16 Ks[3 * 4096];    // [buf][t'][d], chunk^=(t'&7)
  __shared__ __align__(16) u16 VTs[3 * 4096];   // [buf][d][t'perm], chunk^=(d&7)
  const int t = threadIdx.x, w = t >> 6, l = t & 63;
  const int lane15 = l & 15, quad = l >> 4;

  const int bid = blockIdx.x;
  const int xr = bid & 7, g = bid >> 3;     // g in [0,64)
  const int bxt = 8 * (xr & 1) + g % 8;     // [0,16)
  const int bh = 8 * (xr >> 1) + g / 8;     // [0,32)
  const int b = bh >> 4, h = bh & 15;
  const int qrow0 = b * 2048 + bxt * 128;
  const int xm = lane15 & 7;

  short8 qf[2];
#pragma unroll
  for (int ks = 0; ks < 2; ++ks)
    qf[ks] = *(const short8*)&Q[(size_t)(qrow0 + w * 16 + lane15) * 1024 +
                                h * 64 + ks * 32 + quad * 8];

  const short8 vones = {0x3F80, 0x3F80, 0x3F80, 0x3F80,
                        0x3F80, 0x3F80, 0x3F80, 0x3F80};

  floatx4 yacc[4] = {};
  floatx4 lacc = {};

  const int srow = t >> 3;                          // 0..63
  const int scol = (((t & 7) ^ (srow & 7)) << 3);
  const u16* kg = KP + (size_t)(b * 2048 + srow) * 1024 + h * 64 + scol;
  const u16* vg = VT + (size_t)(bh * 64 + srow) * 2048 + scol;

  int kfo[2][4], vfo[2][4];
#pragma unroll
  for (int ks = 0; ks < 2; ++ks)
#pragma unroll
    for (int ti = 0; ti < 4; ++ti)
      kfo[ks][ti] = (ti * 16 + lane15) * 64 + (((ks * 4 + quad) ^ xm) << 3);
#pragma unroll
  for (int ts = 0; ts < 2; ++ts)
#pragma unroll
    for (int ni = 0; ni < 4; ++ni)
      vfo[ts][ni] = (ni * 16 + lane15) * 64 + (((ts * 4 + quad) ^ xm) << 3);

  auto stage = [&](int t0n, int buf) {
    gld16(kg + (size_t)t0n * 1024, &Ks[buf * 4096 + t * 8]);
    gld16(vg + t0n, &VTs[buf * 4096 + t * 8]);
  };
  auto compute = [&](int buf) {
    // S^T = K Q^T : sacc[ti] rows t'=ti*16+quad*4+r, col m=lane15
    floatx4 sacc[4] = {};
#pragma unroll
    for (int ks = 0; ks < 2; ++ks)
#pragma unroll
      for (int ti = 0; ti < 4; ++ti) {
        short8 kf = *(const short8*)&Ks[buf * 4096 + kfo[ks][ti]];
        sacc[ti] = __builtin_amdgcn_mfma_f32_16x16x32_bf16(kf, qf[ks], sacc[ti], 0, 0, 0);
      }
    // p = exp2(s), fragments built lane-locally (pi-permuted k-order)
    float p[4][4];
#pragma unroll
    for (int ti = 0; ti < 4; ++ti)
#pragma unroll
      for (int r = 0; r < 4; ++r) p[ti][r] = fast_exp2(sacc[ti][r]);
#pragma unroll
    for (int ts = 0; ts < 2; ++ts) {
      union { short8 s; unsigned u[4]; } pf;
      pf.u[0] = pack_bf2(p[2 * ts][0], p[2 * ts][1]);
      pf.u[1] = pack_bf2(p[2 * ts][2], p[2 * ts][3]);
      pf.u[2] = pack_bf2(p[2 * ts + 1][0], p[2 * ts + 1][1]);
      pf.u[3] = pack_bf2(p[2 * ts + 1][2], p[2 * ts + 1][3]);
      lacc = __builtin_amdgcn_mfma_f32_16x16x32_bf16(pf.s, vones, lacc, 0, 0, 0);
#pragma unroll
      for (int ni = 0; ni < 4; ++ni) {
        short8 vf = *(const short8*)&VTs[buf * 4096 + vfo[ts][ni]];
        yacc[ni] = __builtin_amdgcn_mfma_f32_16x16x32_bf16(pf.s, vf, yacc[ni], 0, 0, 0);
      }
    }
  };

  // 3-buf pipeline: tile i lives in buf i%3, staged 2 phases ahead.
  stage(0, 0);
  stage(64, 1);
  for (int i = 0; i < 10; ++i) {
    const int base = i * 192;
    WBAR(2);
    compute(0);
    stage(base + 128, 2);
    WBAR(2);
    compute(1);
    stage(base + 192, 0);
    WBAR(2);
    compute(2);
    stage(base + 256, 1);
  }
  WBAR(2);
  compute(0);          // tile 30
  WBAR(0);
  compute(1);          // tile 31

  // epilogue: y = yacc / l ; lacc C-layout row m=quad*4+r matches store rows
#pragma unroll
  for (int r = 0; r < 4; ++r) {
    float linv = 1.0f / lacc[r];
    int row = qrow0 + w * 16 + quad * 4 + r;
#pragma unroll
    for (int ni = 0; ni < 4; ++ni)
      Y[(size_t)row * 1024 + h * 64 + ni * 16 + lane15] = f2bf(yacc[ni][r] * linv);
  }
}

// ---------------- launch ----------------
extern "C" void kernel_launch(void* const* d_in, const int* in_sizes, int n_in,
                              void* d_out, int out_size, void* d_ws, size_t ws_size,
                              hipStream_t stream) {
  const float* query = (const float*)d_in[0];
  const float* key_value = (const float*)d_in[1];
  const float* Wq = (const float*)d_in[2];
  const float* Wkv = (const float*)d_in[3];
  const float* Wc = (const float*)d_in[4];
  float* out = (float*)d_out;

  const size_t MB = 1024 * 1024;
  char* ws = (char*)d_ws;
  u16* qin  = (u16*)(ws + 0 * MB);
  u16* kvin = (u16*)(ws + 8 * MB);
  u16* Wqt  = (u16*)(ws + 16 * MB);
  u16* Wkvt = (u16*)(ws + 18 * MB);
  u16* Wct  = (u16*)(ws + 22 * MB);
  u16* qp   = (u16*)(ws + 24 * MB);
  u16* kp   = (u16*)(ws + 32 * MB);
  u16* vt   = (u16*)(ws + 40 * MB);
  u16* y    = (u16*)(ws + 48 * MB);

  prep<<<dim3(12288), dim3(256), 0, stream>>>(query, key_value, Wq, Wkv, Wc,
                                              qin, kvin, Wqt, Wkvt, Wct);
  const float qscale = 0.125f * 1.4426950408889634f;
  gemm_qkv<<<dim3(768), dim3(256), 0, stream>>>(qin, kvin, Wqt, Wkvt,
                                                qp, kp, vt, qscale);
  attn_kern<<<dim3(512), dim3(512), 0, stream>>>(qp, kp, vt, y);
  gemm_out<<<dim3(512), dim3(256), 0, stream>>>(y, Wct, out);
}